// Round 12
// baseline (71330.090 us; speedup 1.0000x reference)
//
#include <hip/hip_runtime.h>

#define Bn 128
#define Tn 1024
#define INn 256
#define Hn 512
#define NB 256   // persistent blocks (1 per CU), 1024 threads each

typedef short bf16x8 __attribute__((ext_vector_type(8)));
typedef float f32x4 __attribute__((ext_vector_type(4)));

// ---- ws layout (bytes) ----
#define WPK_OFF  0u           // bf16 packed weights (per-block LDS slabs), 23068672 B
#define BIAS_OFF 23068672u    // f32[3][2048]
#define H_OFF    23093248u    // f32 h[3][2][128][512], MALL/sys-coherent
#define STG_OFF  24666112u    // per-XCD bf16 slab 917504 B x 8
#define H3F_OFF  32006144u    // f32[128][512]
#define BAR_OFF  32268288u    // 8KB barrier/membership

// packed-weight region bases (bf16 elems). slab: l0=24576 elems, l1/l2=32768
#define L0B 0u
#define L1B 3145728u
#define L2B 7340032u

// stg slab offsets (bf16 elems)
#define SE_HH 0u        // embed hi [128][256]
#define SE_HL 32768u
#define SH_HH 65536u    // h hi [3][128][512]
#define SH_HL 262144u
#define SLAB  458752u

__device__ __forceinline__ float sigm(float x) { return 1.0f / (1.0f + __expf(-x)); }
__device__ __forceinline__ unsigned short bf_hi(float x) {
  unsigned u = __builtin_bit_cast(unsigned, x);
  return (unsigned short)(u >> 16);
}
__device__ __forceinline__ float bf_f(unsigned short h) {
  unsigned u = ((unsigned)h) << 16;
  return __builtin_bit_cast(float, u);
}

// Pack fp32 weights -> per-(layer, j-tile4) slabs in MFMA fragment order.
// slab = [NCH][64 lanes][8] hi  followed by same-size lo.
// col n = lane&15 -> gate g=n>>2, jl=n&3 -> row r = g*512 + jt4*4 + jl;
// k0 = kc*32 + (lane>>4)*8 over concat [x ; h].
__global__ void pack_weights(const float* __restrict__ wih1, const float* __restrict__ whh1,
                             const float* __restrict__ wih2, const float* __restrict__ whh2,
                             const float* __restrict__ wih3, const float* __restrict__ whh3,
                             unsigned short* __restrict__ wpk) {
  int gid = blockIdx.x * 256 + threadIdx.x;
  int rem, NCH, kih; size_t base, slab; const float *wih, *whh;
  if (gid < 196608)      { rem = gid;          base = L0B; slab = 24576; NCH = 24; kih = 256; wih = wih1; whh = whh1; }
  else if (gid < 458752) { rem = gid - 196608; base = L1B; slab = 32768; NCH = 32; kih = 512; wih = wih2; whh = whh2; }
  else if (gid < 720896) { rem = gid - 458752; base = L2B; slab = 32768; NCH = 32; kih = 512; wih = wih3; whh = whh3; }
  else return;
  const int lane = rem & 63; rem >>= 6;
  const int kc = rem % NCH; rem /= NCH;
  const int jt4 = rem;                    // 0..127
  const int n = lane & 15;
  const int g = n >> 2, jl = n & 3;
  const int r = g * 512 + jt4 * 4 + jl;
  const int k0 = kc * 32 + (lane >> 4) * 8;
  const float* src = (k0 < kih) ? (wih + (size_t)r * kih + k0)
                                : (whh + (size_t)r * 512 + (k0 - kih));
  const size_t dhi = base + (size_t)jt4 * slab + (size_t)kc * 512 + lane * 8;
  const size_t dlo = dhi + (size_t)NCH * 512;
#pragma unroll
  for (int e = 0; e < 8; ++e) {
    float w = src[e];
    unsigned short h = bf_hi(w);
    wpk[dhi + e] = h;
    wpk[dlo + e] = bf_hi(w - bf_f(h));
  }
}

__global__ void pack_bias(const float* __restrict__ bi1, const float* __restrict__ bh1,
                          const float* __restrict__ bi2, const float* __restrict__ bh2,
                          const float* __restrict__ bi3, const float* __restrict__ bh3,
                          float* __restrict__ bias) {
  int gid = blockIdx.x * 256 + threadIdx.x;
  if (gid >= 6144) return;
  int l = gid >> 11, r = gid & 2047;
  const float* bi = (l == 0) ? bi1 : (l == 1) ? bi2 : bi3;
  const float* bh = (l == 0) ? bh1 : (l == 1) ? bh2 : bh3;
  bias[gid] = bi[r] + bh[r];
}

// Grid barrier, ALL RELAXED (r9-proven: no cache invalidation -> LDS weights
// and local-L2 stg untouched). Counter-sharding by bid&7.
__device__ __forceinline__ void gridbar(unsigned* bar, unsigned idx, int shard) {
  __syncthreads();
  if (threadIdx.x == 0) {
    asm volatile("" ::: "memory");
    unsigned o = __hip_atomic_fetch_add(bar + shard * 32, 1u, __ATOMIC_RELAXED, __HIP_MEMORY_SCOPE_AGENT);
    if (o == idx * 32u - 1u) {
      unsigned r = __hip_atomic_fetch_add(bar + 256, 1u, __ATOMIC_RELAXED, __HIP_MEMORY_SCOPE_AGENT);
      if (r == idx * 8u - 1u)
        __hip_atomic_store(bar + 288, idx, __ATOMIC_RELAXED, __HIP_MEMORY_SCOPE_AGENT);
    }
    while (__hip_atomic_load(bar + 288, __ATOMIC_RELAXED, __HIP_MEMORY_SCOPE_AGENT) < idx)
      __builtin_amdgcn_s_sleep(1);
    asm volatile("" ::: "memory");
  }
  __syncthreads();
}

// Weight-stationary persistent LSTM. 256 blocks x 1024 threads (16 waves).
// Blocks 0..127: layers (l0,l1), j-tile4 = bid. Blocks 128..255: l2,
// j-tile4 = bid-128. Weights live in LDS for the whole kernel.
// Per phase: gridbar -> XCD-stage h+embed (sys-read, bf16-split once,
// write to XCD-local L2) -> XCD bar -> M=128 x N=16 MFMA per layer
// (A agent-loads from stg, B from LDS), cell update, h sys f32 write.
__global__ __launch_bounds__(1024) void lstm_ws(
    const float* __restrict__ embed,
    const unsigned short* __restrict__ wpk,
    const float* __restrict__ bias,
    float* __restrict__ hsys,
    unsigned short* __restrict__ stg16,
    float* __restrict__ h3f,
    unsigned* __restrict__ bar)
{
  const int bid = blockIdx.x;
  const int shard = bid & 7;
  const bool combo = (bid < 128);
  const int jt4 = combo ? bid : (bid - 128);
  const int j0 = jt4 * 4;
  const int tid = (int)threadIdx.x;
  const int lane = tid & 63;
  const int w = tid >> 6;             // 0..15
  const int mt = w & 7, kh = w >> 3;  // m-tile, k-half
  const int kgrp = (lane >> 4) * 8;

  __shared__ unsigned short wlds[57344];   // 114688 B weight slab(s)
  __shared__ float pre[2][128][20];        // [kh][b][16 gate-cols] padded
  __shared__ float sbias[2][16];
  __shared__ int s_xcd, s_slot, s_nx;

  if (tid == 0) {
    unsigned x;
    asm volatile("s_getreg_b32 %0, hwreg(HW_REG_XCC_ID)" : "=s"(x));
    s_xcd = (int)(x & 7u);
  }
  if (tid < 32) {
    const int ls = tid >> 4, n = tid & 15;    // layer slot, col
    const int L = combo ? ls : 2;
    if (ls == 0 || combo)
      sbias[ls][n] = bias[L * 2048 + (n >> 2) * 512 + j0 + (n & 3)];
  }
  // fill LDS weights (one-time)
  {
    const unsigned nelem = combo ? 57344u : 32768u;
    const size_t g0 = combo ? (L0B + (size_t)jt4 * 24576) : (L2B + (size_t)jt4 * 32768);
    const size_t g1 = L1B + (size_t)jt4 * 32768;   // combo only
    for (unsigned i = tid * 8; i < nelem; i += 1024 * 8) {
      const size_t src = combo ? ((i < 24576u) ? g0 + i : g1 + (i - 24576u)) : (g0 + i);
      *reinterpret_cast<bf16x8*>(&wlds[i]) = *reinterpret_cast<const bf16x8*>(wpk + src);
    }
  }
  __syncthreads();
  const int myxcd = s_xcd;
  if (tid == 0)
    s_slot = (int)__hip_atomic_fetch_add(bar + 1024 + myxcd * 16, 1u,
                                         __ATOMIC_RELAXED, __HIP_MEMORY_SCOPE_AGENT);
  // zero h (sys, deterministic per launch)
  unsigned long long* hz = (unsigned long long*)hsys;
  for (int i = bid * 1024 + tid; i < 196608; i += NB * 1024)
    __hip_atomic_store(hz + i, 0ull, __ATOMIC_RELAXED, __HIP_MEMORY_SCOPE_SYSTEM);

  float c0 = 0.f, c1 = 0.f;             // cell state (b=tid>>2, j0+(tid&3)), tid<512
  unsigned bidx = 1;
  gridbar(bar, bidx++, shard);
  if (tid == 0)
    s_nx = (int)__hip_atomic_load(bar + 1024 + myxcd * 16,
                                  __ATOMIC_RELAXED, __HIP_MEMORY_SCOPE_AGENT);
  __syncthreads();
  const int slot = s_slot, nx = s_nx;

  const unsigned long long* hs_u = (const unsigned long long*)hsys;
  const unsigned long long* em_u = (const unsigned long long*)embed;
  unsigned short* stgx = stg16 + (size_t)myxcd * SLAB;

  for (int p = 0; p <= 1024; ++p) {
    const int rp = (p + 1) & 1, wp = p & 1;

    // ---- stage: sys-read h[rp] (+ embed[:,p,:]), split to bf16 hi/lo, local write ----
    for (unsigned u = slot * 1024u + tid; u < 28672u; u += (unsigned)nx * 1024u) {
      float xs[8];
      unsigned dofs, dsep;
      if (u < 4096u) {
        if (p > 1022) continue;
        const int b = u >> 5, kk = (u & 31) << 3;
        const unsigned long long* sp = em_u + ((((size_t)b * Tn + p) * INn + kk) >> 1);
        dofs = SE_HH + b * 256 + kk; dsep = SE_HL - SE_HH;
#pragma unroll
        for (int q = 0; q < 4; ++q) {
          unsigned long long v = __hip_atomic_load(sp + q, __ATOMIC_RELAXED, __HIP_MEMORY_SCOPE_SYSTEM);
          xs[2*q]   = __builtin_bit_cast(float, (unsigned)(v & 0xffffffffu));
          xs[2*q+1] = __builtin_bit_cast(float, (unsigned)(v >> 32));
        }
      } else {
        const unsigned hu = u - 4096u;
        const int li = hu >> 13, rem = hu & 8191, b = rem >> 6, kk = (rem & 63) << 3;
        const unsigned long long* sp = hs_u + ((((size_t)(li * 2 + rp) * Bn + b) * Hn + kk) >> 1);
        dofs = SH_HH + li * 65536 + b * 512 + kk; dsep = SH_HL - SH_HH;
#pragma unroll
        for (int q = 0; q < 4; ++q) {
          unsigned long long v = __hip_atomic_load(sp + q, __ATOMIC_RELAXED, __HIP_MEMORY_SCOPE_SYSTEM);
          xs[2*q]   = __builtin_bit_cast(float, (unsigned)(v & 0xffffffffu));
          xs[2*q+1] = __builtin_bit_cast(float, (unsigned)(v >> 32));
        }
      }
      bf16x8 vh, vl;
#pragma unroll
      for (int e = 0; e < 8; ++e) {
        unsigned short h1 = bf_hi(xs[e]);
        vh[e] = (short)h1;
        vl[e] = (short)bf_hi(xs[e] - bf_f(h1));
      }
      *reinterpret_cast<bf16x8*>(stgx + dofs) = vh;
      *reinterpret_cast<bf16x8*>(stgx + dofs + dsep) = vl;
    }
    __syncthreads();                    // drain stg stores to local L2
    if (tid == 0) {
      __hip_atomic_fetch_add(bar + 512 + myxcd * 64, 1u,
                             __ATOMIC_RELAXED, __HIP_MEMORY_SCOPE_AGENT);
      const unsigned tgt = (unsigned)nx * (unsigned)(p + 1);
      while (__hip_atomic_load(bar + 512 + myxcd * 64,
                               __ATOMIC_RELAXED, __HIP_MEMORY_SCOPE_AGENT) < tgt)
        __builtin_amdgcn_s_sleep(1);
      asm volatile("" ::: "memory");
    }
    __syncthreads();

    auto do_layer = [&](int L, int lslot, int NCH, int wofs, float& c) {
      const int t = p - L;
      if (t < 0 || t > 1022) return;
      const int half = NCH >> 1;
      const int row = mt * 16 + (lane & 15);
      f32x4 accA = {0.f,0.f,0.f,0.f}, accB = {0.f,0.f,0.f,0.f};
#pragma unroll
      for (int i = 0; i < 16; ++i) {
        if (i >= half) break;
        const int kc = kh * half + i;
        const int k0 = kc * 32 + kgrp;
        unsigned aofs, asep;
        if (L == 0) {
          if (kc < 8) { aofs = SE_HH + row * 256 + k0;                 asep = SE_HL - SE_HH; }
          else        { aofs = SH_HH + row * 512 + (k0 - 256);         asep = SH_HL - SH_HH; }
        } else if (L == 1) {
          aofs = (kc < 16) ? (SH_HH + row * 512 + k0)
                           : (SH_HH + 65536 + row * 512 + (k0 - 512)); asep = SH_HL - SH_HH;
        } else {
          aofs = (kc < 16) ? (SH_HH + 65536 + row * 512 + k0)
                           : (SH_HH + 131072 + row * 512 + (k0 - 512)); asep = SH_HL - SH_HH;
        }
        const unsigned long long* ah = (const unsigned long long*)(stgx + aofs);
        const unsigned long long* al = (const unsigned long long*)(stgx + aofs + asep);
        unsigned long long h0 = __hip_atomic_load(ah,     __ATOMIC_RELAXED, __HIP_MEMORY_SCOPE_AGENT);
        unsigned long long h1 = __hip_atomic_load(ah + 1, __ATOMIC_RELAXED, __HIP_MEMORY_SCOPE_AGENT);
        unsigned long long l0v = __hip_atomic_load(al,     __ATOMIC_RELAXED, __HIP_MEMORY_SCOPE_AGENT);
        unsigned long long l1v = __hip_atomic_load(al + 1, __ATOMIC_RELAXED, __HIP_MEMORY_SCOPE_AGENT);
        struct { unsigned long long a, b; } th = {h0, h1}, tl = {l0v, l1v};
        const bf16x8 aH = __builtin_bit_cast(bf16x8, th);
        const bf16x8 aL = __builtin_bit_cast(bf16x8, tl);
        const bf16x8 bH = *reinterpret_cast<const bf16x8*>(&wlds[wofs + kc * 512 + lane * 8]);
        const bf16x8 bL = *reinterpret_cast<const bf16x8*>(&wlds[wofs + NCH * 512 + kc * 512 + lane * 8]);
        accA = __builtin_amdgcn_mfma_f32_16x16x32_bf16(aH, bH, accA, 0, 0, 0);
        accA = __builtin_amdgcn_mfma_f32_16x16x32_bf16(aL, bH, accA, 0, 0, 0);
        accB = __builtin_amdgcn_mfma_f32_16x16x32_bf16(aH, bL, accB, 0, 0, 0);
        accB = __builtin_amdgcn_mfma_f32_16x16x32_bf16(aL, bL, accB, 0, 0, 0);
      }
      {
        const int prow = mt * 16 + ((lane >> 4) << 2);
        const int pcol = lane & 15;
#pragma unroll
        for (int r = 0; r < 4; ++r)
          pre[kh][prow + r][pcol] = accA[r] + accB[r];
      }
      __syncthreads();
      if (tid < 512) {
        const int b = tid >> 2, jl = tid & 3;
        const float g0 = pre[0][b][jl]      + pre[1][b][jl]      + sbias[lslot][jl];
        const float g1 = pre[0][b][4 + jl]  + pre[1][b][4 + jl]  + sbias[lslot][4 + jl];
        const float g2 = pre[0][b][8 + jl]  + pre[1][b][8 + jl]  + sbias[lslot][8 + jl];
        const float g3 = pre[0][b][12 + jl] + pre[1][b][12 + jl] + sbias[lslot][12 + jl];
        const float ig = sigm(g0), fg = sigm(g1), gg = tanhf(g2), og = sigm(g3);
        c = fg * c + ig * gg;
        const float hv = og * tanhf(c);
        __hip_atomic_store((unsigned*)hsys + ((size_t)(L * 2 + wp) * 65536 + (size_t)b * 512 + (j0 + jl)),
                           __builtin_bit_cast(unsigned, hv),
                           __ATOMIC_RELAXED, __HIP_MEMORY_SCOPE_SYSTEM);
        if (L == 2 && t == 1022)
          h3f[(size_t)b * 512 + (j0 + jl)] = hv;
      }
      __syncthreads();
    };

    if (combo) {
      do_layer(0, 0, 24, 0, c0);
      do_layer(1, 1, 32, 24576, c1);
    } else {
      do_layer(2, 0, 32, 0, c0);
    }

    gridbar(bar, bidx++, shard);
  }
}

// FC epilogue: out2[b][o] = h3_final[b,:] . fc_w[o,:] + fc_b[o]
__global__ void fc_kernel(const float* __restrict__ h3f, const float* __restrict__ fcw,
                          const float* __restrict__ fcb, float* __restrict__ out) {
  const int gid = blockIdx.x * 256 + (int)threadIdx.x;
  if (gid >= Bn * INn) return;
  const int b = gid >> 8, o = gid & 255;
  const float* hr = h3f + (size_t)b * Hn;
  const float* wr = fcw + (size_t)o * Hn;
  float acc = fcb[o];
#pragma unroll 4
  for (int k = 0; k < Hn; k += 4) {
    const float4 hv = *reinterpret_cast<const float4*>(hr + k);
    const float4 wv = *reinterpret_cast<const float4*>(wr + k);
    acc = fmaf(hv.x, wv.x, acc); acc = fmaf(hv.y, wv.y, acc);
    acc = fmaf(hv.z, wv.z, acc); acc = fmaf(hv.w, wv.w, acc);
  }
  out[(size_t)Bn * Tn * INn + gid] = acc;
}

extern "C" void kernel_launch(void* const* d_in, const int* in_sizes, int n_in,
                              void* d_out, int out_size, void* d_ws, size_t ws_size,
                              hipStream_t stream) {
  const float* embed = (const float*)d_in[0];
  const float* wih1  = (const float*)d_in[1];
  const float* whh1  = (const float*)d_in[2];
  const float* bih1  = (const float*)d_in[3];
  const float* bhh1  = (const float*)d_in[4];
  const float* wih2  = (const float*)d_in[5];
  const float* whh2  = (const float*)d_in[6];
  const float* bih2  = (const float*)d_in[7];
  const float* bhh2  = (const float*)d_in[8];
  const float* wih3  = (const float*)d_in[9];
  const float* whh3  = (const float*)d_in[10];
  const float* bih3  = (const float*)d_in[11];
  const float* bhh3  = (const float*)d_in[12];
  const float* fcw   = (const float*)d_in[13];
  const float* fcb   = (const float*)d_in[14];
  float* outp = (float*)d_out;

  char* ws = (char*)d_ws;
  unsigned short* wpk = (unsigned short*)(ws + WPK_OFF);
  float* bias         = (float*)(ws + BIAS_OFF);
  float* hsys         = (float*)(ws + H_OFF);
  unsigned short* stg = (unsigned short*)(ws + STG_OFF);
  float* h3f          = (float*)(ws + H3F_OFF);
  unsigned* bar       = (unsigned*)(ws + BAR_OFF);

  // Output 0: embed passthrough (128 MB d2d)
  hipMemcpyAsync(d_out, d_in[0], (size_t)Bn * Tn * INn * sizeof(float),
                 hipMemcpyDeviceToDevice, stream);
  hipMemsetAsync(bar, 0, 8192, stream);

  pack_weights<<<2816, 256, 0, stream>>>(wih1, whh1, wih2, whh2, wih3, whh3, wpk);
  pack_bias<<<24, 256, 0, stream>>>(bih1, bhh1, bih2, bhh2, bih3, bhh3, bias);

  void* args[] = { (void*)&embed, (void*)&wpk, (void*)&bias,
                   (void*)&hsys, (void*)&stg, (void*)&h3f, (void*)&bar };
  dim3 grid(NB), block(1024);
  hipLaunchCooperativeKernel((const void*)lstm_ws, grid, block, args, 0, stream);

  fc_kernel<<<128, 256, 0, stream>>>(h3f, fcw, fcb, outp);
}

// Round 13
// 21111.320 us; speedup vs baseline: 3.3788x; 3.3788x over previous
//
#include <hip/hip_runtime.h>

#define Bn 128
#define Tn 1024
#define INn 256
#define Hn 512
#define NB 256   // persistent blocks (1 per CU), 1024 threads each

typedef short bf16x8 __attribute__((ext_vector_type(8)));
typedef float f32x4 __attribute__((ext_vector_type(4)));

// ---- ws layout (bytes) ----
#define WPK_OFF  0u           // bf16 packed weights 23068672 B
#define BIAS_OFF 23068672u    // f32[3][2048]
#define H_OFF    23093248u    // f32 h[3][2][128][512], MALL/sys-coherent
#define H3F_OFF  24666112u    // f32[128][512]
#define BAR_OFF  24928256u    // 8KB barrier

// packed-weight bases (bf16 elems); per-G slab: l0=24576, l1/l2=32768 elems
#define L0B 0u
#define L1B 3145728u
#define L2B 7340032u

__device__ __forceinline__ float sigm(float x) { return 1.0f / (1.0f + __expf(-x)); }
__device__ __forceinline__ unsigned short bf_hi(float x) {
  unsigned u = __builtin_bit_cast(unsigned, x);
  return (unsigned short)(u >> 16);
}
__device__ __forceinline__ float bf_f(unsigned short h) {
  unsigned u = ((unsigned)h) << 16;
  return __builtin_bit_cast(float, u);
}

// Pack fp32 weights -> per-(layer, 16-col group G) slabs in MFMA fragment
// order (r12-proven layout). slab = [NCH][64][8] hi then same-size lo.
// col n = lane&15 -> gate g=n>>2, jl=n&3 -> row r = g*512 + G*4 + jl;
// k0 = kc*32 + (lane>>4)*8 over concat [x ; h].
__global__ void pack_weights(const float* __restrict__ wih1, const float* __restrict__ whh1,
                             const float* __restrict__ wih2, const float* __restrict__ whh2,
                             const float* __restrict__ wih3, const float* __restrict__ whh3,
                             unsigned short* __restrict__ wpk) {
  int gid = blockIdx.x * 256 + threadIdx.x;
  int rem, NCH, kih; size_t base, slab; const float *wih, *whh;
  if (gid < 196608)      { rem = gid;          base = L0B; slab = 24576; NCH = 24; kih = 256; wih = wih1; whh = whh1; }
  else if (gid < 458752) { rem = gid - 196608; base = L1B; slab = 32768; NCH = 32; kih = 512; wih = wih2; whh = whh2; }
  else if (gid < 720896) { rem = gid - 458752; base = L2B; slab = 32768; NCH = 32; kih = 512; wih = wih3; whh = whh3; }
  else return;
  const int lane = rem & 63; rem >>= 6;
  const int kc = rem % NCH; rem /= NCH;
  const int G = rem;                      // 0..127
  const int n = lane & 15;
  const int g = n >> 2, jl = n & 3;
  const int r = g * 512 + G * 4 + jl;
  const int k0 = kc * 32 + (lane >> 4) * 8;
  const float* src = (k0 < kih) ? (wih + (size_t)r * kih + k0)
                                : (whh + (size_t)r * 512 + (k0 - kih));
  const size_t dhi = base + (size_t)G * slab + (size_t)kc * 512 + lane * 8;
  const size_t dlo = dhi + (size_t)NCH * 512;
#pragma unroll
  for (int e = 0; e < 8; ++e) {
    float w = src[e];
    unsigned short h = bf_hi(w);
    wpk[dhi + e] = h;
    wpk[dlo + e] = bf_hi(w - bf_f(h));
  }
}

__global__ void pack_bias(const float* __restrict__ bi1, const float* __restrict__ bh1,
                          const float* __restrict__ bi2, const float* __restrict__ bh2,
                          const float* __restrict__ bi3, const float* __restrict__ bh3,
                          float* __restrict__ bias) {
  int gid = blockIdx.x * 256 + threadIdx.x;
  if (gid >= 6144) return;
  int l = gid >> 11, r = gid & 2047;
  const float* bi = (l == 0) ? bi1 : (l == 1) ? bi2 : bi3;
  const float* bh = (l == 0) ? bh1 : (l == 1) ? bh2 : bh3;
  bias[gid] = bi[r] + bh[r];
}

// Grid barrier, ALL RELAXED (r9-proven: no cache invalidation -> weights
// stay L2-resident). Counter-sharding by bid&7 (32 per shard).
__device__ __forceinline__ void gridbar(unsigned* bar, unsigned idx, int shard) {
  __syncthreads();
  if (threadIdx.x == 0) {
    asm volatile("" ::: "memory");
    unsigned o = __hip_atomic_fetch_add(bar + shard * 32, 1u, __ATOMIC_RELAXED, __HIP_MEMORY_SCOPE_AGENT);
    if (o == idx * 32u - 1u) {
      unsigned r = __hip_atomic_fetch_add(bar + 256, 1u, __ATOMIC_RELAXED, __HIP_MEMORY_SCOPE_AGENT);
      if (r == idx * 8u - 1u)
        __hip_atomic_store(bar + 288, idx, __ATOMIC_RELAXED, __HIP_MEMORY_SCOPE_AGENT);
    }
    while (__hip_atomic_load(bar + 288, __ATOMIC_RELAXED, __HIP_MEMORY_SCOPE_AGENT) < idx)
      __builtin_amdgcn_s_sleep(1);
    asm volatile("" ::: "memory");
  }
  __syncthreads();
}

// Persistent fused LSTM: 256 blocks x 1024 threads (16 waves = 4/SIMD).
// Block = (b-tile 16: bt=bid>>5, j-tile 16: jt=bid&31). bid%8 fixes jt%8 ->
// per-XCD weight slice 2.88 MB (L2-resident, r9-proven).
// Per layer per phase: cooperative sys-read of the block's A-slice
// (16 rows x K f32) -> bf16 hi/lo split once -> block-local LDS; then
// 16 waves (nsub 0..3 x kq 0..3) run MFMAs with A from LDS, B from L2.
// A = 2-split, B = 2-split, 4 MFMAs (r7-proven numerics, absmax 2.4e-4).
__global__ __launch_bounds__(1024) void lstm_persist(
    const float* __restrict__ embed,
    const unsigned short* __restrict__ wpk,
    const float* __restrict__ bias,
    float* __restrict__ hsys,
    float* __restrict__ h3f,
    unsigned* __restrict__ bar)
{
  const int bid = blockIdx.x;
  const int shard = bid & 7;
  const int jt = bid & 31;           // j-tile 16
  const int bt = bid >> 5;           // b-tile 16
  const int tid = (int)threadIdx.x;
  const int lane = tid & 63;
  const int w = tid >> 6;            // 0..15
  const int nsub = w & 3, kq = w >> 2;

  __shared__ short als[2][32][16][32];   // [split][kc][brow][k] 64 KB
  __shared__ float pre[4][16][68];       // [kq][brow][64 cols + pad]
  __shared__ float sbias[3][64];

  if (tid < 192) {
    const int l = tid >> 6, c = tid & 63;
    const int n = c & 15, g = n >> 2;
    sbias[l][c] = bias[l * 2048 + g * 512 + jt * 16 + (c >> 4) * 4 + (n & 3)];
  }
  // zero h (sys, deterministic per launch)
  unsigned long long* hz = (unsigned long long*)hsys;
  for (int i = bid * 1024 + tid; i < 196608; i += NB * 1024)
    __hip_atomic_store(hz + i, 0ull, __ATOMIC_RELAXED, __HIP_MEMORY_SCOPE_SYSTEM);

  float c0 = 0.f, c1 = 0.f, c2 = 0.f;   // cell state (bt*16+(tid>>4), jt*16+(tid&15)), tid<256
  unsigned bidx = 1;
  gridbar(bar, bidx++, shard);

  const unsigned long long* hs_u = (const unsigned long long*)hsys;
  const int arow = lane & 15;
  const int kg8 = (lane >> 4) * 8;

  for (int p = 0; p <= 1024; ++p) {
    const int rp = (p + 1) & 1, wp = p & 1;

#pragma unroll
    for (int l = 0; l < 3; ++l) {
      const int t = p - l;
      if (t < 0 || t > 1022) continue;
      const int K = (l == 0) ? 768 : 1024;
      const int NCH = K >> 5;
      const int rowch = K >> 3;            // 8-f32 chunks per row

      // ---- stage A-slice -> LDS (bf16 split once) ----
      for (int u = tid; u < rowch * 16; u += 1024) {
        const int row = u / rowch;
        const int k0 = (u - row * rowch) << 3;
        const int b = bt * 16 + row;
        float xs[8];
        if (l == 0 && k0 < 256) {          // embed: plain nt loads (read-only input)
          const float* s = embed + ((size_t)b * Tn + t) * INn + k0;
          const f32x4 x0 = __builtin_nontemporal_load(reinterpret_cast<const f32x4*>(s));
          const f32x4 x1 = __builtin_nontemporal_load(reinterpret_cast<const f32x4*>(s) + 1);
          xs[0]=x0.x; xs[1]=x0.y; xs[2]=x0.z; xs[3]=x0.w;
          xs[4]=x1.x; xs[5]=x1.y; xs[6]=x1.z; xs[7]=x1.w;
        } else {                           // h: sys loads (MALL-coherent)
          int srcl, off;
          if (l == 0)        { srcl = 0;     off = k0 - 256; }
          else if (k0 < 512) { srcl = l - 1; off = k0;       }
          else               { srcl = l;     off = k0 - 512; }
          const unsigned long long* sp =
              hs_u + ((((size_t)(srcl * 2 + rp) * Bn + b) * Hn + off) >> 1);
#pragma unroll
          for (int q = 0; q < 4; ++q) {
            unsigned long long v = __hip_atomic_load(sp + q, __ATOMIC_RELAXED, __HIP_MEMORY_SCOPE_SYSTEM);
            xs[2*q]   = __builtin_bit_cast(float, (unsigned)(v & 0xffffffffu));
            xs[2*q+1] = __builtin_bit_cast(float, (unsigned)(v >> 32));
          }
        }
        bf16x8 vh, vl;
#pragma unroll
        for (int e = 0; e < 8; ++e) {
          unsigned short h1 = bf_hi(xs[e]);
          vh[e] = (short)h1;
          vl[e] = (short)bf_hi(xs[e] - bf_f(h1));
        }
        const int kc = k0 >> 5, ko = k0 & 31;
        *reinterpret_cast<bf16x8*>(&als[0][kc][row][ko]) = vh;
        *reinterpret_cast<bf16x8*>(&als[1][kc][row][ko]) = vl;
      }
      __syncthreads();

      // ---- MFMA: A from LDS, B from L2-resident packed weights ----
      const size_t wbase = (l == 0) ? L0B : ((l == 1) ? L1B : L2B);
      const size_t slab  = (l == 0) ? 24576 : 32768;
      const int G = jt * 4 + nsub;
      const unsigned short* wb = wpk + wbase + (size_t)G * slab + lane * 8;
      const int q4 = NCH >> 2;             // 6 or 8
      f32x4 accE = {0.f,0.f,0.f,0.f}, accO = {0.f,0.f,0.f,0.f};
#pragma unroll
      for (int i = 0; i < 8; ++i) {
        if (i >= q4) break;                // compile-time per l
        const int kc = kq * q4 + i;
        const bf16x8 aH = *reinterpret_cast<const bf16x8*>(&als[0][kc][arow][kg8]);
        const bf16x8 aL = *reinterpret_cast<const bf16x8*>(&als[1][kc][arow][kg8]);
        const bf16x8 bH = *reinterpret_cast<const bf16x8*>(wb + (size_t)kc * 512);
        const bf16x8 bL = *reinterpret_cast<const bf16x8*>(wb + (size_t)(NCH + kc) * 512);
        if (i & 1) {
          accO = __builtin_amdgcn_mfma_f32_16x16x32_bf16(aH, bH, accO, 0, 0, 0);
          accO = __builtin_amdgcn_mfma_f32_16x16x32_bf16(aL, bH, accO, 0, 0, 0);
          accO = __builtin_amdgcn_mfma_f32_16x16x32_bf16(aH, bL, accO, 0, 0, 0);
          accO = __builtin_amdgcn_mfma_f32_16x16x32_bf16(aL, bL, accO, 0, 0, 0);
        } else {
          accE = __builtin_amdgcn_mfma_f32_16x16x32_bf16(aH, bH, accE, 0, 0, 0);
          accE = __builtin_amdgcn_mfma_f32_16x16x32_bf16(aL, bH, accE, 0, 0, 0);
          accE = __builtin_amdgcn_mfma_f32_16x16x32_bf16(aH, bL, accE, 0, 0, 0);
          accE = __builtin_amdgcn_mfma_f32_16x16x32_bf16(aL, bL, accE, 0, 0, 0);
        }
      }
      {
        const int prow = (lane >> 4) << 2;
        const int pc = nsub * 16 + (lane & 15);
#pragma unroll
        for (int r = 0; r < 4; ++r)
          pre[kq][prow + r][pc] = accE[r] + accO[r];
      }
      __syncthreads();

      // ---- cell update (tid<256: b=tid>>4, jl=tid&15) ----
      if (tid < 256) {
        const int b = tid >> 4, jl = tid & 15;
        float gv[4];
#pragma unroll
        for (int gi = 0; gi < 4; ++gi) {
          const int c = (jl >> 2) * 16 + gi * 4 + (jl & 3);
          gv[gi] = sbias[l][c] + pre[0][b][c] + pre[1][b][c] + pre[2][b][c] + pre[3][b][c];
        }
        const float ig = sigm(gv[0]), fg = sigm(gv[1]), gg = tanhf(gv[2]), og = sigm(gv[3]);
        float& c = (l == 0) ? c0 : ((l == 1) ? c1 : c2);
        c = fg * c + ig * gg;
        const float hv = og * tanhf(c);
        __hip_atomic_store((unsigned*)hsys +
            ((size_t)(l * 2 + wp) * 65536 + (size_t)(bt * 16 + b) * 512 + jt * 16 + jl),
            __builtin_bit_cast(unsigned, hv), __ATOMIC_RELAXED, __HIP_MEMORY_SCOPE_SYSTEM);
        if (l == 2 && t == 1022)
          h3f[(size_t)(bt * 16 + b) * 512 + jt * 16 + jl] = hv;
      }
    }
    gridbar(bar, bidx++, shard);
  }
}

// FC epilogue: out2[b][o] = h3_final[b,:] . fc_w[o,:] + fc_b[o]
__global__ void fc_kernel(const float* __restrict__ h3f, const float* __restrict__ fcw,
                          const float* __restrict__ fcb, float* __restrict__ out) {
  const int gid = blockIdx.x * 256 + (int)threadIdx.x;
  if (gid >= Bn * INn) return;
  const int b = gid >> 8, o = gid & 255;
  const float* hr = h3f + (size_t)b * Hn;
  const float* wr = fcw + (size_t)o * Hn;
  float acc = fcb[o];
#pragma unroll 4
  for (int k = 0; k < Hn; k += 4) {
    const float4 hv = *reinterpret_cast<const float4*>(hr + k);
    const float4 wv = *reinterpret_cast<const float4*>(wr + k);
    acc = fmaf(hv.x, wv.x, acc); acc = fmaf(hv.y, wv.y, acc);
    acc = fmaf(hv.z, wv.z, acc); acc = fmaf(hv.w, wv.w, acc);
  }
  out[(size_t)Bn * Tn * INn + gid] = acc;
}

extern "C" void kernel_launch(void* const* d_in, const int* in_sizes, int n_in,
                              void* d_out, int out_size, void* d_ws, size_t ws_size,
                              hipStream_t stream) {
  const float* embed = (const float*)d_in[0];
  const float* wih1  = (const float*)d_in[1];
  const float* whh1  = (const float*)d_in[2];
  const float* bih1  = (const float*)d_in[3];
  const float* bhh1  = (const float*)d_in[4];
  const float* wih2  = (const float*)d_in[5];
  const float* whh2  = (const float*)d_in[6];
  const float* bih2  = (const float*)d_in[7];
  const float* bhh2  = (const float*)d_in[8];
  const float* wih3  = (const float*)d_in[9];
  const float* whh3  = (const float*)d_in[10];
  const float* bih3  = (const float*)d_in[11];
  const float* bhh3  = (const float*)d_in[12];
  const float* fcw   = (const float*)d_in[13];
  const float* fcb   = (const float*)d_in[14];
  float* outp = (float*)d_out;

  char* ws = (char*)d_ws;
  unsigned short* wpk = (unsigned short*)(ws + WPK_OFF);
  float* bias         = (float*)(ws + BIAS_OFF);
  float* hsys         = (float*)(ws + H_OFF);
  float* h3f          = (float*)(ws + H3F_OFF);
  unsigned* bar       = (unsigned*)(ws + BAR_OFF);

  // Output 0: embed passthrough (128 MB d2d)
  hipMemcpyAsync(d_out, d_in[0], (size_t)Bn * Tn * INn * sizeof(float),
                 hipMemcpyDeviceToDevice, stream);
  hipMemsetAsync(bar, 0, 8192, stream);

  pack_weights<<<2816, 256, 0, stream>>>(wih1, whh1, wih2, whh2, wih3, whh3, wpk);
  pack_bias<<<24, 256, 0, stream>>>(bih1, bhh1, bih2, bhh2, bih3, bhh3, bias);

  void* args[] = { (void*)&embed, (void*)&wpk, (void*)&bias,
                   (void*)&hsys, (void*)&h3f, (void*)&bar };
  dim3 grid(NB), block(1024);
  hipLaunchCooperativeKernel((const void*)lstm_persist, grid, block, args, 0, stream);

  fc_kernel<<<128, 256, 0, stream>>>(h3f, fcw, fcb, outp);
}

// Round 14
// 19680.991 us; speedup vs baseline: 3.6243x; 1.0727x over previous
//
#include <hip/hip_runtime.h>

#define Bn 128
#define Tn 1024
#define INn 256
#define Hn 512
#define NB 256   // persistent blocks (1 per CU), 1024 threads each

typedef short bf16x8 __attribute__((ext_vector_type(8)));
typedef float f32x4 __attribute__((ext_vector_type(4)));

// ---- ws layout (bytes) ----
#define WPK_OFF  0u           // bf16 packed weights 23068672 B
#define BIAS_OFF 23068672u    // f32[3][2048]
#define H_OFF    23093248u    // f32 h[3][2][128][512], MALL/sys-coherent
#define H3F_OFF  24666112u    // f32[128][512]
#define BAR_OFF  24928256u    // 8KB barrier

// packed-weight bases (bf16 elems); per-G slab: l0=24576, l1/l2=32768 elems
#define L0B 0u
#define L1B 3145728u
#define L2B 7340032u

__device__ __forceinline__ float sigm(float x) { return 1.0f / (1.0f + __expf(-x)); }
__device__ __forceinline__ unsigned short bf_hi(float x) {
  unsigned u = __builtin_bit_cast(unsigned, x);
  return (unsigned short)(u >> 16);
}
__device__ __forceinline__ float bf_f(unsigned short h) {
  unsigned u = ((unsigned)h) << 16;
  return __builtin_bit_cast(float, u);
}

// Pack fp32 weights -> per-(layer, 16-col group G) slabs in MFMA fragment
// order (r13-proven layout). slab = [NCH][64][8] hi then same-size lo.
// col n = lane&15 -> gate g=n>>2, jl=n&3 -> row r = g*512 + G*4 + jl;
// k0 = kc*32 + (lane>>4)*8 over concat [x ; h].
__global__ void pack_weights(const float* __restrict__ wih1, const float* __restrict__ whh1,
                             const float* __restrict__ wih2, const float* __restrict__ whh2,
                             const float* __restrict__ wih3, const float* __restrict__ whh3,
                             unsigned short* __restrict__ wpk) {
  int gid = blockIdx.x * 256 + threadIdx.x;
  int rem, NCH, kih; size_t base, slab; const float *wih, *whh;
  if (gid < 196608)      { rem = gid;          base = L0B; slab = 24576; NCH = 24; kih = 256; wih = wih1; whh = whh1; }
  else if (gid < 458752) { rem = gid - 196608; base = L1B; slab = 32768; NCH = 32; kih = 512; wih = wih2; whh = whh2; }
  else if (gid < 720896) { rem = gid - 458752; base = L2B; slab = 32768; NCH = 32; kih = 512; wih = wih3; whh = whh3; }
  else return;
  const int lane = rem & 63; rem >>= 6;
  const int kc = rem % NCH; rem /= NCH;
  const int G = rem;                      // 0..127
  const int n = lane & 15;
  const int g = n >> 2, jl = n & 3;
  const int r = g * 512 + G * 4 + jl;
  const int k0 = kc * 32 + (lane >> 4) * 8;
  const float* src = (k0 < kih) ? (wih + (size_t)r * kih + k0)
                                : (whh + (size_t)r * 512 + (k0 - kih));
  const size_t dhi = base + (size_t)G * slab + (size_t)kc * 512 + lane * 8;
  const size_t dlo = dhi + (size_t)NCH * 512;
#pragma unroll
  for (int e = 0; e < 8; ++e) {
    float w = src[e];
    unsigned short h = bf_hi(w);
    wpk[dhi + e] = h;
    wpk[dlo + e] = bf_hi(w - bf_f(h));
  }
}

__global__ void pack_bias(const float* __restrict__ bi1, const float* __restrict__ bh1,
                          const float* __restrict__ bi2, const float* __restrict__ bh2,
                          const float* __restrict__ bi3, const float* __restrict__ bh3,
                          float* __restrict__ bias) {
  int gid = blockIdx.x * 256 + threadIdx.x;
  if (gid >= 6144) return;
  int l = gid >> 11, r = gid & 2047;
  const float* bi = (l == 0) ? bi1 : (l == 1) ? bi2 : bi3;
  const float* bh = (l == 0) ? bh1 : (l == 1) ? bh2 : bh3;
  bias[gid] = bi[r] + bh[r];
}

// Grid barrier, ALL RELAXED (r9-proven). Counter-sharding by bid&7.
__device__ __forceinline__ void gridbar(unsigned* bar, unsigned idx, int shard) {
  __syncthreads();
  if (threadIdx.x == 0) {
    asm volatile("" ::: "memory");
    unsigned o = __hip_atomic_fetch_add(bar + shard * 32, 1u, __ATOMIC_RELAXED, __HIP_MEMORY_SCOPE_AGENT);
    if (o == idx * 32u - 1u) {
      unsigned r = __hip_atomic_fetch_add(bar + 256, 1u, __ATOMIC_RELAXED, __HIP_MEMORY_SCOPE_AGENT);
      if (r == idx * 8u - 1u)
        __hip_atomic_store(bar + 288, idx, __ATOMIC_RELAXED, __HIP_MEMORY_SCOPE_AGENT);
    }
    while (__hip_atomic_load(bar + 288, __ATOMIC_RELAXED, __HIP_MEMORY_SCOPE_AGENT) < idx)
      __builtin_amdgcn_s_sleep(1);
    asm volatile("" ::: "memory");
  }
  __syncthreads();
}

// Persistent fused LSTM: 256 blocks x 1024 threads (16 waves = 4/SIMD).
// Block = (b-tile 16: bt=bid>>5, j-tile 16: jt=bid&31); bid%8 fixes jt%8 ->
// 2.88 MB weights/XCD (L2-resident, r13-proven).
// Per phase: ONE deduped stage {embed, h1, h2, h3} -> LDS (56 chunks,
// bf16-split once); layers consume overlapping windows [0,24) [8,40) [24,56).
// 4 syncs/phase: stage | mfma l0,l1 | cells l0,l1 | mfma l2 | cell l2 | bar.
// als stride 36 shorts (72 B) -> uniform 2-way banks (free).
__global__ __launch_bounds__(1024) void lstm_persist(
    const float* __restrict__ embed,
    const unsigned short* __restrict__ wpk,
    const float* __restrict__ bias,
    float* __restrict__ hsys,
    float* __restrict__ h3f,
    unsigned* __restrict__ bar)
{
  const int bid = blockIdx.x;
  const int shard = bid & 7;
  const int jt = bid & 31;           // j-tile 16
  const int bt = bid >> 5;           // b-tile 16
  const int tid = (int)threadIdx.x;
  const int lane = tid & 63;
  const int w = tid >> 6;            // 0..15
  const int nsub = w & 3, kq = w >> 2;

  __shared__ short als[2][56][16][36];   // 129024 B, deduped A chunks
  __shared__ float pre[2][4][16][65];    // 33280 B
  __shared__ float sbias[3][64];         // 768 B

  if (tid < 192) {
    const int l = tid >> 6, c = tid & 63;
    const int n = c & 15, g = n >> 2;
    sbias[l][c] = bias[l * 2048 + g * 512 + jt * 16 + (c >> 4) * 4 + (n & 3)];
  }
  // zero h (sys, deterministic per launch)
  unsigned long long* hz = (unsigned long long*)hsys;
  for (int i = bid * 1024 + tid; i < 196608; i += NB * 1024)
    __hip_atomic_store(hz + i, 0ull, __ATOMIC_RELAXED, __HIP_MEMORY_SCOPE_SYSTEM);

  float c0 = 0.f, c1 = 0.f, c2 = 0.f;   // cell state (bt*16+(tid>>4), jt*16+(tid&15)), tid<256
  unsigned bidx = 1;
  gridbar(bar, bidx++, shard);

  const unsigned long long* hs_u = (const unsigned long long*)hsys;
  const int arow = lane & 15;
  const int kg8 = (lane >> 4) * 8;

  // per-layer MFMA pass: A from deduped LDS window, B from L2 weights
  auto mfma_layer = [&](int NCH, int q4, size_t wbase, size_t slab, int lbase, int pl) {
    const int G = jt * 4 + nsub;
    const unsigned short* wb = wpk + wbase + (size_t)G * slab + (size_t)lane * 8;
    f32x4 accE = {0.f,0.f,0.f,0.f}, accO = {0.f,0.f,0.f,0.f};
#pragma unroll
    for (int i = 0; i < 8; ++i) {
      if (i >= q4) break;                // compile-time per call site
      const int kc = kq * q4 + i;
      const int ch = lbase + kc;
      const bf16x8 aH = *reinterpret_cast<const bf16x8*>(&als[0][ch][arow][kg8]);
      const bf16x8 aL = *reinterpret_cast<const bf16x8*>(&als[1][ch][arow][kg8]);
      const bf16x8 bH = *reinterpret_cast<const bf16x8*>(wb + (size_t)kc * 512);
      const bf16x8 bL = *reinterpret_cast<const bf16x8*>(wb + (size_t)(NCH + kc) * 512);
      if (i & 1) {
        accO = __builtin_amdgcn_mfma_f32_16x16x32_bf16(aH, bH, accO, 0, 0, 0);
        accO = __builtin_amdgcn_mfma_f32_16x16x32_bf16(aL, bH, accO, 0, 0, 0);
        accO = __builtin_amdgcn_mfma_f32_16x16x32_bf16(aH, bL, accO, 0, 0, 0);
        accO = __builtin_amdgcn_mfma_f32_16x16x32_bf16(aL, bL, accO, 0, 0, 0);
      } else {
        accE = __builtin_amdgcn_mfma_f32_16x16x32_bf16(aH, bH, accE, 0, 0, 0);
        accE = __builtin_amdgcn_mfma_f32_16x16x32_bf16(aL, bH, accE, 0, 0, 0);
        accE = __builtin_amdgcn_mfma_f32_16x16x32_bf16(aH, bL, accE, 0, 0, 0);
        accE = __builtin_amdgcn_mfma_f32_16x16x32_bf16(aL, bL, accE, 0, 0, 0);
      }
    }
    const int prow = (lane >> 4) << 2;
    const int pc = lane & 15;
#pragma unroll
    for (int r = 0; r < 4; ++r)
      pre[pl][kq][prow + r][nsub * 16 + pc] = accE[r] + accO[r];
  };

  // cell update for one layer (tid<256): b=tid>>4, jl=tid&15
  auto cell_layer = [&](int l, int pl, int wp, int t, float& c) {
    const int b = tid >> 4, jl = tid & 15;
    float gv[4];
#pragma unroll
    for (int gi = 0; gi < 4; ++gi) {
      const int cc = (jl >> 2) * 16 + gi * 4 + (jl & 3);
      gv[gi] = sbias[l][cc] + pre[pl][0][b][cc] + pre[pl][1][b][cc]
             + pre[pl][2][b][cc] + pre[pl][3][b][cc];
    }
    const float ig = sigm(gv[0]), fg = sigm(gv[1]), gg = tanhf(gv[2]), og = sigm(gv[3]);
    c = fg * c + ig * gg;
    const float hv = og * tanhf(c);
    __hip_atomic_store((unsigned*)hsys +
        ((size_t)(l * 2 + wp) * 65536 + (size_t)(bt * 16 + b) * 512 + jt * 16 + jl),
        __builtin_bit_cast(unsigned, hv), __ATOMIC_RELAXED, __HIP_MEMORY_SCOPE_SYSTEM);
    if (l == 2 && t == 1022)
      h3f[(size_t)(bt * 16 + b) * 512 + jt * 16 + jl] = hv;
  };

  for (int p = 0; p <= 1024; ++p) {
    const int rp = (p + 1) & 1, wp = p & 1;
    const bool a0 = (p <= 1022), a1 = (p >= 1) && (p <= 1023), a2 = (p >= 2);

    // ---- deduped stage: embed(512 units) + h1,h2,h3 (1024 each) ----
    for (int u = tid; u < 3584; u += 1024) {
      float xs[8];
      int ch, row, ko;
      if (u < 512) {                       // embed: 16 rows x 32 units
        if (p > 1022) continue;
        row = u >> 5;
        const int k0 = (u & 31) << 3;
        const float* s = embed + ((size_t)(bt * 16 + row) * Tn + p) * INn + k0;
        const f32x4 x0 = __builtin_nontemporal_load(reinterpret_cast<const f32x4*>(s));
        const f32x4 x1 = __builtin_nontemporal_load(reinterpret_cast<const f32x4*>(s) + 1);
        xs[0]=x0.x; xs[1]=x0.y; xs[2]=x0.z; xs[3]=x0.w;
        xs[4]=x1.x; xs[5]=x1.y; xs[6]=x1.z; xs[7]=x1.w;
        ch = k0 >> 5; ko = k0 & 31;
      } else {                             // h_li: 16 rows x 64 units each
        const int v = u - 512;
        const int li = v >> 10;            // 0..2
        const int idx = v & 1023;
        row = idx >> 6;
        const int k0 = (idx & 63) << 3;
        const unsigned long long* sp = hs_u +
            ((size_t)(li * 2 + rp) * 32768 + (size_t)(bt * 16 + row) * 256 + (k0 >> 1));
#pragma unroll
        for (int q = 0; q < 4; ++q) {
          unsigned long long vv = __hip_atomic_load(sp + q, __ATOMIC_RELAXED, __HIP_MEMORY_SCOPE_SYSTEM);
          xs[2*q]   = __builtin_bit_cast(float, (unsigned)(vv & 0xffffffffu));
          xs[2*q+1] = __builtin_bit_cast(float, (unsigned)(vv >> 32));
        }
        ch = 8 + li * 16 + (k0 >> 5); ko = k0 & 31;
      }
      bf16x8 vh, vl;
#pragma unroll
      for (int e = 0; e < 8; ++e) {
        unsigned short h1 = bf_hi(xs[e]);
        vh[e] = (short)h1;
        vl[e] = (short)bf_hi(xs[e] - bf_f(h1));
      }
      *reinterpret_cast<bf16x8*>(&als[0][ch][row][ko]) = vh;
      *reinterpret_cast<bf16x8*>(&als[1][ch][row][ko]) = vl;
    }
    __syncthreads();

    // ---- mfma l0 -> pre[0], l1 -> pre[1] ----
    if (a0) mfma_layer(24, 6, L0B, 24576, 0, 0);
    if (a1) mfma_layer(32, 8, L1B, 32768, 8, 1);
    __syncthreads();
    if (tid < 256) {
      if (a0) cell_layer(0, 0, wp, p, c0);
      if (a1) cell_layer(1, 1, wp, p - 1, c1);
    }
    __syncthreads();

    // ---- mfma l2 -> pre[0] (cells above already consumed pre[0]) ----
    if (a2) mfma_layer(32, 8, L2B, 32768, 24, 0);
    __syncthreads();
    if (tid < 256 && a2) cell_layer(2, 0, wp, p - 2, c2);

    gridbar(bar, bidx++, shard);
  }
}

// FC epilogue: out2[b][o] = h3_final[b,:] . fc_w[o,:] + fc_b[o]
__global__ void fc_kernel(const float* __restrict__ h3f, const float* __restrict__ fcw,
                          const float* __restrict__ fcb, float* __restrict__ out) {
  const int gid = blockIdx.x * 256 + (int)threadIdx.x;
  if (gid >= Bn * INn) return;
  const int b = gid >> 8, o = gid & 255;
  const float* hr = h3f + (size_t)b * Hn;
  const float* wr = fcw + (size_t)o * Hn;
  float acc = fcb[o];
#pragma unroll 4
  for (int k = 0; k < Hn; k += 4) {
    const float4 hv = *reinterpret_cast<const float4*>(hr + k);
    const float4 wv = *reinterpret_cast<const float4*>(wr + k);
    acc = fmaf(hv.x, wv.x, acc); acc = fmaf(hv.y, wv.y, acc);
    acc = fmaf(hv.z, wv.z, acc); acc = fmaf(hv.w, wv.w, acc);
  }
  out[(size_t)Bn * Tn * INn + gid] = acc;
}

extern "C" void kernel_launch(void* const* d_in, const int* in_sizes, int n_in,
                              void* d_out, int out_size, void* d_ws, size_t ws_size,
                              hipStream_t stream) {
  const float* embed = (const float*)d_in[0];
  const float* wih1  = (const float*)d_in[1];
  const float* whh1  = (const float*)d_in[2];
  const float* bih1  = (const float*)d_in[3];
  const float* bhh1  = (const float*)d_in[4];
  const float* wih2  = (const float*)d_in[5];
  const float* whh2  = (const float*)d_in[6];
  const float* bih2  = (const float*)d_in[7];
  const float* bhh2  = (const float*)d_in[8];
  const float* wih3  = (const float*)d_in[9];
  const float* whh3  = (const float*)d_in[10];
  const float* bih3  = (const float*)d_in[11];
  const float* bhh3  = (const float*)d_in[12];
  const float* fcw   = (const float*)d_in[13];
  const float* fcb   = (const float*)d_in[14];
  float* outp = (float*)d_out;

  char* ws = (char*)d_ws;
  unsigned short* wpk = (unsigned short*)(ws + WPK_OFF);
  float* bias         = (float*)(ws + BIAS_OFF);
  float* hsys         = (float*)(ws + H_OFF);
  float* h3f          = (float*)(ws + H3F_OFF);
  unsigned* bar       = (unsigned*)(ws + BAR_OFF);

  // Output 0: embed passthrough (128 MB d2d)
  hipMemcpyAsync(d_out, d_in[0], (size_t)Bn * Tn * INn * sizeof(float),
                 hipMemcpyDeviceToDevice, stream);
  hipMemsetAsync(bar, 0, 8192, stream);

  pack_weights<<<2816, 256, 0, stream>>>(wih1, whh1, wih2, whh2, wih3, whh3, wpk);
  pack_bias<<<24, 256, 0, stream>>>(bih1, bhh1, bih2, bhh2, bih3, bhh3, bias);

  void* args[] = { (void*)&embed, (void*)&wpk, (void*)&bias,
                   (void*)&hsys, (void*)&h3f, (void*)&bar };
  dim3 grid(NB), block(1024);
  hipLaunchCooperativeKernel((const void*)lstm_persist, grid, block, args, 0, stream);

  fc_kernel<<<128, 256, 0, stream>>>(h3f, fcw, fcb, outp);
}